// Round 10
// baseline (150.367 us; speedup 1.0000x reference)
//
#include <hip/hip_runtime.h>
#include <stdint.h>

// int4 grouped-quant GEMM: out[64][28672] = x[64][8192] . W^T + bias
// W packed [N][K/2] int32, one byte/int32 = 2 nibbles (low = even k), zp = 8,
// per-128-k scales. fp16 ref -> harness gives x/scales/bias/out as FP32.
// Round-10: DRAM-pattern fix. Rounds 7-9 streamed W as 448 streams x 256 B
// granules (~50% DRAM efficiency, invariant 135 us across 3 sync schemes).
// Now: 16-col blocks (grid 1792 = 7/CU balanced), 4-group supersteps staging
// W as 1 KB-contiguous bursts per column, k-split waves (wave w owns group
// 4s+w; no dequant redundancy), X direct from L2 (frag-ordered), scales in
// LDS, 36 KB LDS -> 4 blocks/CU, 2 barriers per superstep, vmcnt never 0.

typedef __attribute__((ext_vector_type(8))) short     short8;
typedef __attribute__((ext_vector_type(4))) float     f32x4;
typedef __attribute__((ext_vector_type(4))) int       i32x4;
typedef __attribute__((ext_vector_type(2))) _Float16  f16x2;
typedef __attribute__((ext_vector_type(8))) _Float16  f16x8;

// async global->LDS, 16 B/lane. LDS dest = wave-uniform base + lane*16 (HW);
// global source is PER-LANE -> swizzle via pre-swizzled source (m173).
static __device__ __forceinline__ void gload_lds16(const void* gp, void* lp) {
    __builtin_amdgcn_global_load_lds(
        (const __attribute__((address_space(1))) unsigned int*)gp,
        (__attribute__((address_space(3))) unsigned int*)lp, 16, 0, 0);
}

// int4 pair -> fp16 pair: u = 0x6400|nib (fp16 1024+v, exact), (u-1032) exact
// in f16 (= v-8), then *s (single rounding - matches reference fp16 mul).
static __device__ __forceinline__ f16x8 dequant(const i32x4& w, f16x2 s2) {
    const f16x2 c1032 = {(_Float16)1032.0f, (_Float16)1032.0f};
    union { unsigned u[4]; f16x8 v; } r;
    #pragma unroll
    for (int j = 0; j < 4; ++j) {
        unsigned v = (unsigned)w[j];
        unsigned u = ((v & 0xFu) | 0x64006400u) | ((v << 12) & 0xF0000u);
        f16x2 h = __builtin_bit_cast(f16x2, u);
        h = (h - c1032) * s2;
        r.u[j] = __builtin_bit_cast(unsigned, h);
    }
    return r.v;
}

// x fp32 [64][K] -> fp16 (lossless) in A-fragment order: xf[g][st][mt][lane][8]
__global__ __launch_bounds__(256)
void xpack_kernel(const float* __restrict__ x, unsigned short* __restrict__ xf, int K) {
    int c    = blockIdx.x * 256 + threadIdx.x;
    int g    = c >> 10;
    int st   = (c >> 8) & 3;
    int mt   = (c >> 6) & 3;
    int lane = c & 63;
    int quad = lane >> 4, l15 = lane & 15;
    const float* p = x + (size_t)(l15 + mt * 16) * K + g * 128 + st * 32 + quad * 8;
    f32x4 lo = *(const f32x4*)p;
    f32x4 hi = *(const f32x4*)(p + 4);
    f16x8 r = { (_Float16)lo[0], (_Float16)lo[1], (_Float16)lo[2], (_Float16)lo[3],
                (_Float16)hi[0], (_Float16)hi[1], (_Float16)hi[2], (_Float16)hi[3] };
    *(short8*)(xf + (size_t)c * 8) = __builtin_bit_cast(short8, r);
}

// scales [N][ng] -> [ng][N] (write-coalesced)
__global__ __launch_bounds__(256)
void strans_kernel(const float* __restrict__ sc, float* __restrict__ sct, int N, int ng) {
    int n = blockIdx.x * 256 + threadIdx.x;
    int g = blockIdx.y;
    sct[(size_t)g * N + n] = sc[(size_t)n * ng + g];
}

__global__ __launch_bounds__(256, 4)
void int4mm_kernel(const unsigned short* __restrict__ xf,  // fp16 frag-ordered x
                   const int*   __restrict__ wp,           // [N][K/2]
                   const float* __restrict__ sc,           // [N][ng] (fallback)
                   const float* __restrict__ sct,          // [ng][N] or nullptr
                   const float* __restrict__ bias,         // [N]
                   float*       __restrict__ out,          // [64][N]
                   int K, int N)
{
    __shared__ char lds[36864];              // 32 KB W dbuf + 4 KB scales
    char*  ldsW = lds;                       // [2][16 cols][1024 B], XOR-swizzled
    float* ldsS = (float*)(lds + 32768);     // [64 g][16 cols]

    const int tid  = threadIdx.x;
    const int lane = tid & 63;
    const int wave = tid >> 6;               // k-split: wave w owns group 4s+w
    const int quad = lane >> 4;
    const int l15  = lane & 15;
    const int blk16 = blockIdx.x * 16;
    const int ncol  = blk16 + l15;
    const int ng = K / 128;                  // 64
    const int ns = ng / 4;                   // 16 supersteps

    const char* wp8 = (const char*)wp;       // one col's row = 16384 B

    // Stage sources: round r stages local col c = r*4+wave as ONE 1 KB burst;
    // lane supplies global chunk (lane ^ (c&7)) -> LDS slot 'lane' (linear),
    // i.e. slot l holds global chunk l^(c&7)  (involution swizzle).
    size_t wsrc[4];
    #pragma unroll
    for (int r = 0; r < 4; ++r) {
        const int c = r * 4 + wave;
        wsrc[r] = (size_t)(blk16 + c) * 16384 + (size_t)((lane ^ (c & 7)) << 4);
    }

    // Prologue: scales (1 VMEM/thread) + W superstep 0 -> buf0 (4 VMEM/thread).
    if (sct) {   // thread t copies scales[g = t>>2][4 cols (t&3)*4..+3]
        const int g = tid >> 2, c4 = (tid & 3) * 4;
        gload_lds16((const char*)sct + ((size_t)g * N + blk16 + c4) * 4,
                    (char*)ldsS + wave * 1024);
    }
    #pragma unroll
    for (int r = 0; r < 4; ++r)
        gload_lds16(wp8 + wsrc[r], ldsW + (r * 4 + wave) * 1024);

    f32x4 acc0 = {0,0,0,0}, acc1 = {0,0,0,0}, acc2 = {0,0,0,0}, acc3 = {0,0,0,0};

    const int i_base = wave * 16 + quad;     // chunk idx = i_base + st*4
    const int swz    = l15 & 7;

    #pragma unroll 1
    for (int s = 0; s < ns; ++s) {
        const int p  = s & 1;
        const int sn = (s + 1 < ns) ? s + 1 : ns - 1;   // clamped dead restage

        __builtin_amdgcn_sched_barrier(0);
        __builtin_amdgcn_s_barrier();        // buf[p^1] reads (superstep s-1) done

        #pragma unroll
        for (int r = 0; r < 4; ++r)          // stage W(s+1): 4 x 1 KB bursts/wave
            gload_lds16(wp8 + wsrc[r] + (size_t)sn * 1024,
                        ldsW + (p ^ 1) * 16384 + (r * 4 + wave) * 1024);

        asm volatile("s_waitcnt vmcnt(4)" ::: "memory");  // W(s) landed (mine);
        __builtin_amdgcn_s_barrier();                     // ...for all waves
        __builtin_amdgcn_sched_barrier(0);   // keep ds_reads below the sync

        const int g = s * 4 + wave;          // this wave's group this superstep
        const float sf = sct ? ldsS[(g << 4) + l15] : sc[(size_t)ncol * ng + g];
        const f16x2 s2 = {(_Float16)sf, (_Float16)sf};

        const char* wb = ldsW + p * 16384 + l15 * 1024;
        const unsigned short* xg = xf + (size_t)g * 8192;   // [st][mt][lane][8]

        #pragma unroll
        for (int st = 0; st < 4; ++st) {
            i32x4 w = *(const i32x4*)(wb + (size_t)(((i_base + st * 4) ^ swz) << 4));
            f16x8 b = dequant(w, s2);
            const unsigned short* xs = xg + st * 2048 + lane * 8;
            f16x8 x0 = __builtin_bit_cast(f16x8, *(const short8*)(xs));
            f16x8 x1 = __builtin_bit_cast(f16x8, *(const short8*)(xs + 512));
            f16x8 x2 = __builtin_bit_cast(f16x8, *(const short8*)(xs + 1024));
            f16x8 x3 = __builtin_bit_cast(f16x8, *(const short8*)(xs + 1536));
            acc0 = __builtin_amdgcn_mfma_f32_16x16x32_f16(x0, b, acc0, 0, 0, 0);
            acc1 = __builtin_amdgcn_mfma_f32_16x16x32_f16(x1, b, acc1, 0, 0, 0);
            acc2 = __builtin_amdgcn_mfma_f32_16x16x32_f16(x2, b, acc2, 0, 0, 0);
            acc3 = __builtin_amdgcn_mfma_f32_16x16x32_f16(x3, b, acc3, 0, 0, 0);
        }
    }

    // Epilogue: cross-wave reduce (waves hold disjoint K-quarters of the same
    // 64m x 16n tile). Partials -> LDS [wave][m][col], then sum + bias.
    __syncthreads();
    {
        float* pw = (float*)ldsW + wave * 1024;
        #pragma unroll
        for (int r = 0; r < 4; ++r) {
            pw[( 0 + quad * 4 + r) * 16 + l15] = acc0[r];
            pw[(16 + quad * 4 + r) * 16 + l15] = acc1[r];
            pw[(32 + quad * 4 + r) * 16 + l15] = acc2[r];
            pw[(48 + quad * 4 + r) * 16 + l15] = acc3[r];
        }
    }
    __syncthreads();
    {
        const int col = tid & 15;
        const int m0  = (tid >> 4) * 4;
        const float bv = bias[blk16 + col];
        const float* pl = (const float*)ldsW;
        #pragma unroll
        for (int r = 0; r < 4; ++r) {
            const int m = m0 + r;
            float v = pl[m * 16 + col]        + pl[1024 + m * 16 + col]
                    + pl[2048 + m * 16 + col] + pl[3072 + m * 16 + col];
            out[(size_t)m * N + blk16 + col] = v + bv;
        }
    }
}

extern "C" void kernel_launch(void* const* d_in, const int* in_sizes, int n_in,
                              void* d_out, int out_size, void* d_ws, size_t ws_size,
                              hipStream_t stream)
{
    const float* x    = (const float*)d_in[0];
    const int*   wp   = (const int*)d_in[1];
    const float* sc   = (const float*)d_in[2];
    const float* bias = (const float*)d_in[3];
    float*       out  = (float*)d_out;

    const int N  = in_sizes[3];                       // 28672
    const long long Kh = (long long)in_sizes[1] / N;  // 4096
    const int K  = (int)(2 * Kh);                     // 8192
    const int ng = K / 128;                           // 64

    unsigned short* xf = (unsigned short*)d_ws;       // 1 MB frag-ordered fp16 x
    const size_t xf_bytes  = (size_t)ng * 16384;
    const size_t sct_bytes = (size_t)ng * N * 4;
    float* sct = nullptr;

    xpack_kernel<<<(ng * 1024) / 256, 256, 0, stream>>>(x, xf, K);
    if (ws_size >= xf_bytes + sct_bytes && (N & 255) == 0) {
        sct = (float*)((char*)d_ws + xf_bytes);
        strans_kernel<<<dim3(N / 256, ng), 256, 0, stream>>>(sc, sct, N, ng);
    }
    int4mm_kernel<<<N / 16, 256, 0, stream>>>(xf, wp, sc, sct, bias, out, K, N);
}

// Round 11
// 107.166 us; speedup vs baseline: 1.4031x; 1.4031x over previous
//
#include <hip/hip_runtime.h>
#include <stdint.h>

// int4 grouped-quant GEMM: out[64][28672] = x[64][8192] . W^T + bias
// W packed [N][K/2] int32, one byte/int32 = 2 nibbles (low = even k), zp = 8,
// per-128-k scales. fp16 ref -> harness gives x/scales/bias/out as FP32.
// Round-11: kstep-split. R7-9's 135us invariant = 4x-redundant A-fragment LDS
// reads (80 KB/block-iter) + in-phase convoy. Now wave w owns kstep w of every
// group: A-frags unique per wave -> registers (prefetched from L2 xf), X out
// of LDS entirely; LDS/block-group 112->32 KB; 48 KB LDS -> 3 blocks/CU;
// per-iter VMEM = exactly 8 -> vmcnt(8) keeps W(g+1) in flight across both
// raw barriers. Epilogue: cross-wave reduce via LDS.

typedef __attribute__((ext_vector_type(8))) short     short8;
typedef __attribute__((ext_vector_type(4))) float     f32x4;
typedef __attribute__((ext_vector_type(4))) int       i32x4;
typedef __attribute__((ext_vector_type(2))) _Float16  f16x2;
typedef __attribute__((ext_vector_type(8))) _Float16  f16x8;

// async global->LDS, 16 B/lane. LDS dest = wave-uniform base + lane*16 (HW);
// global source is PER-LANE -> swizzle via pre-swizzled source (m173).
static __device__ __forceinline__ void gload_lds16(const void* gp, void* lp) {
    __builtin_amdgcn_global_load_lds(
        (const __attribute__((address_space(1))) unsigned int*)gp,
        (__attribute__((address_space(3))) unsigned int*)lp, 16, 0, 0);
}

// int4 pair -> fp16 pair: u = 0x6400|nib (fp16 1024+v, exact), (u-1032) exact
// in f16 (= v-8), then *s (single rounding - matches reference fp16 mul).
static __device__ __forceinline__ f16x8 dequant(const i32x4& w, f16x2 s2) {
    const f16x2 c1032 = {(_Float16)1032.0f, (_Float16)1032.0f};
    union { unsigned u[4]; f16x8 v; } r;
    #pragma unroll
    for (int j = 0; j < 4; ++j) {
        unsigned v = (unsigned)w[j];
        unsigned u = ((v & 0xFu) | 0x64006400u) | ((v << 12) & 0xF0000u);
        f16x2 h = __builtin_bit_cast(f16x2, u);
        h = (h - c1032) * s2;
        r.u[j] = __builtin_bit_cast(unsigned, h);
    }
    return r.v;
}

// x fp32 [64][K] -> fp16 (lossless) in A-fragment order: xf[g][st][mt][lane][8]
__global__ __launch_bounds__(256)
void xpack_kernel(const float* __restrict__ x, unsigned short* __restrict__ xf, int K) {
    int c    = blockIdx.x * 256 + threadIdx.x;
    int g    = c >> 10;
    int st   = (c >> 8) & 3;
    int mt   = (c >> 6) & 3;
    int lane = c & 63;
    int quad = lane >> 4, l15 = lane & 15;
    const float* p = x + (size_t)(l15 + mt * 16) * K + g * 128 + st * 32 + quad * 8;
    f32x4 lo = *(const f32x4*)p;
    f32x4 hi = *(const f32x4*)(p + 4);
    f16x8 r = { (_Float16)lo[0], (_Float16)lo[1], (_Float16)lo[2], (_Float16)lo[3],
                (_Float16)hi[0], (_Float16)hi[1], (_Float16)hi[2], (_Float16)hi[3] };
    *(short8*)(xf + (size_t)c * 8) = __builtin_bit_cast(short8, r);
}

__global__ __launch_bounds__(256)
void int4mm_kernel(const unsigned short* __restrict__ xf,  // fp16 frag-ordered x
                   const int*   __restrict__ wp,           // [N][K/2]
                   const float* __restrict__ sc,           // [N][ng]
                   const float* __restrict__ bias,         // [N]
                   float*       __restrict__ out,          // [64][N]
                   int K, int N)
{
    __shared__ char lds[49152];              // 32 KB W dbuf | 16 KB scales
    char*  ldsW = lds;                       // [2][64 col][16 slot][16 B]
    float* ldsS = (float*)(lds + 32768);     // [64 g][64 col]

    const int tid  = threadIdx.x;
    const int lane = tid & 63;
    const int wave = tid >> 6;               // kstep owner: k-quarter of each group
    const int quad = lane >> 4;
    const int l15  = lane & 15;
    const int blk64 = blockIdx.x * 64;
    const int ng   = K / 128;                // 64 groups

    const char* wp8 = (const char*)wp;       // one col's W row = 16384 B

    // W stage sources (R7-9-verified involution): instr j of wave w covers
    // local cols w*16+j*4+quad; lane supplies chunk l15^(j*4+quad); LDS slot s
    // of col c ends up holding global chunk s^(c&15).
    unsigned woff[4];
    #pragma unroll
    for (int j = 0; j < 4; ++j) {
        int cloc  = wave * 16 + j * 4 + quad;
        int chunk = l15 ^ (j * 4 + quad);
        woff[j] = ((unsigned)(blk64 + cloc) << 14) + ((unsigned)chunk << 4);
    }

    // B-frag ds_read offsets: col c = nt*16+l15, chunk (wave*4+quad) at slot
    // ((wave*4+quad)^l15) -> beat-optimal (8 beats/instr).
    int rdW[4];
    #pragma unroll
    for (int nt = 0; nt < 4; ++nt)
        rdW[nt] = (nt * 16 + l15) * 256 + (((wave * 4 + quad) ^ l15) << 4);

    // ---- prologue ----
    // scales: ldsS[g][c] = sc[(blk64+c)*ng + g] via 64 B contiguous loads.
    {
        const int c  = tid & 63;
        const int g0 = (tid >> 6) * 16;
        const float* sp = sc + (size_t)(blk64 + c) * ng + g0;
        f32x4 s0 = *(const f32x4*)(sp);
        f32x4 s1 = *(const f32x4*)(sp + 4);
        f32x4 s2 = *(const f32x4*)(sp + 8);
        f32x4 s3 = *(const f32x4*)(sp + 12);
        #pragma unroll
        for (int j = 0; j < 4; ++j) {
            ldsS[(g0 + 0  + j) * 64 + c] = s0[j];
            ldsS[(g0 + 4  + j) * 64 + c] = s1[j];
            ldsS[(g0 + 8  + j) * 64 + c] = s2[j];
            ldsS[(g0 + 12 + j) * 64 + c] = s3[j];
        }
    }
    #pragma unroll
    for (int j = 0; j < 4; ++j)              // stage W(0) -> buf0
        gload_lds16(wp8 + woff[j], ldsW + (wave * 4 + j) * 1024);

    const char* xbase = (const char*)xf + wave * 4096 + lane * 16;
    f16x8 xn[4], xc[4];
    #pragma unroll
    for (int mt = 0; mt < 4; ++mt)           // X(0) -> regs
        xn[mt] = *(const f16x8*)(xbase + mt * 1024);

    f32x4 acc[4][4];
    #pragma unroll
    for (int mt = 0; mt < 4; ++mt)
        #pragma unroll
        for (int nt = 0; nt < 4; ++nt)
            acc[mt][nt] = f32x4{0.f, 0.f, 0.f, 0.f};

    __syncthreads();   // prologue drain: scales visible, buf0 staged

    // Main loop: per-iter VMEM = 4 X-reg loads + 4 W stages = 8.
    // vmcnt(8) at iter g leaves {X(g+1), W(g+1)} in flight, forces W(g) done;
    // X(g) is forced by the compiler's own wait before the xc=xn copy.
    #pragma unroll 1
    for (int g = 0; g < ng; ++g) {
        const int p  = g & 1;
        const int gn = (g + 1 < ng) ? g + 1 : ng - 1;   // clamped dead tail

        #pragma unroll
        for (int mt = 0; mt < 4; ++mt) xc[mt] = xn[mt]; // consume X(g)

        const char* xs = xbase + (size_t)gn * 16384;    // issue X(g+1)
        #pragma unroll
        for (int mt = 0; mt < 4; ++mt)
            xn[mt] = *(const f16x8*)(xs + mt * 1024);

        __builtin_amdgcn_s_barrier();        // iter g-1 readers of buf[p^1] done

        #pragma unroll
        for (int j = 0; j < 4; ++j)          // stage W(g+1) -> buf[p^1]
            gload_lds16(wp8 + woff[j] + (size_t)gn * 256,
                        ldsW + (p ^ 1) * 16384 + (wave * 4 + j) * 1024);

        asm volatile("s_waitcnt vmcnt(8)" ::: "memory");  // W(g) landed (mine)
        __builtin_amdgcn_s_barrier();                     // ...for all waves
        __builtin_amdgcn_sched_barrier(0);   // keep ds_reads below the sync

        const char* wb = ldsW + p * 16384;
        i32x4 v0 = *(const i32x4*)(wb + rdW[0]);
        i32x4 v1 = *(const i32x4*)(wb + rdW[1]);
        i32x4 v2 = *(const i32x4*)(wb + rdW[2]);
        i32x4 v3 = *(const i32x4*)(wb + rdW[3]);

        const float* sg = ldsS + g * 64;
        const float sf0 = sg[l15], sf1 = sg[16 + l15];
        const float sf2 = sg[32 + l15], sf3 = sg[48 + l15];

        {
            f16x8 b = dequant(v0, f16x2{(_Float16)sf0, (_Float16)sf0});
            #pragma unroll
            for (int mt = 0; mt < 4; ++mt)
                acc[mt][0] = __builtin_amdgcn_mfma_f32_16x16x32_f16(xc[mt], b, acc[mt][0], 0, 0, 0);
        }
        {
            f16x8 b = dequant(v1, f16x2{(_Float16)sf1, (_Float16)sf1});
            #pragma unroll
            for (int mt = 0; mt < 4; ++mt)
                acc[mt][1] = __builtin_amdgcn_mfma_f32_16x16x32_f16(xc[mt], b, acc[mt][1], 0, 0, 0);
        }
        {
            f16x8 b = dequant(v2, f16x2{(_Float16)sf2, (_Float16)sf2});
            #pragma unroll
            for (int mt = 0; mt < 4; ++mt)
                acc[mt][2] = __builtin_amdgcn_mfma_f32_16x16x32_f16(xc[mt], b, acc[mt][2], 0, 0, 0);
        }
        {
            f16x8 b = dequant(v3, f16x2{(_Float16)sf3, (_Float16)sf3});
            #pragma unroll
            for (int mt = 0; mt < 4; ++mt)
                acc[mt][3] = __builtin_amdgcn_mfma_f32_16x16x32_f16(xc[mt], b, acc[mt][3], 0, 0, 0);
        }
    }

    // ---- epilogue: cross-wave (kstep) reduce. Wave w owns mt = w. ----
    // Partials: addr(owner o, slot s, nt) = ((o*3+s)*4+nt)*1024 + lane*16 (48 KB).
    __syncthreads();
    #pragma unroll
    for (int o = 0; o < 4; ++o) {
        if (o == wave) continue;             // wave-uniform branch
        const int s = wave - (wave > o ? 1 : 0);
        #pragma unroll
        for (int nt = 0; nt < 4; ++nt)
            *(f32x4*)(lds + (size_t)(((o * 3 + s) * 4 + nt) * 1024) + lane * 16)
                = acc[o][nt];
    }
    __syncthreads();

    f32x4 own[4];
    #pragma unroll
    for (int nt = 0; nt < 4; ++nt) own[nt] = acc[0][nt];
    #pragma unroll
    for (int o = 1; o < 4; ++o)
        if (wave == o) {                     // wave-uniform, compile-time acc idx
            own[0] = acc[o][0]; own[1] = acc[o][1];
            own[2] = acc[o][2]; own[3] = acc[o][3];
        }
    #pragma unroll
    for (int s = 0; s < 3; ++s)
        #pragma unroll
        for (int nt = 0; nt < 4; ++nt)
            own[nt] += *(const f32x4*)(lds + (size_t)(((wave * 3 + s) * 4 + nt) * 1024)
                                       + lane * 16);

    #pragma unroll
    for (int nt = 0; nt < 4; ++nt) {
        const int col = blk64 + nt * 16 + l15;
        const float bv = bias[col];
        #pragma unroll
        for (int r = 0; r < 4; ++r)
            out[(size_t)(wave * 16 + quad * 4 + r) * N + col] = own[nt][r] + bv;
    }
}

extern "C" void kernel_launch(void* const* d_in, const int* in_sizes, int n_in,
                              void* d_out, int out_size, void* d_ws, size_t ws_size,
                              hipStream_t stream)
{
    const float* x    = (const float*)d_in[0];
    const int*   wp   = (const int*)d_in[1];
    const float* sc   = (const float*)d_in[2];
    const float* bias = (const float*)d_in[3];
    float*       out  = (float*)d_out;

    const int N  = in_sizes[3];                       // 28672
    const long long Kh = (long long)in_sizes[1] / N;  // 4096
    const int K  = (int)(2 * Kh);                     // 8192
    const int ng = K / 128;                           // 64

    unsigned short* xf = (unsigned short*)d_ws;       // 1 MB frag-ordered fp16 x

    xpack_kernel<<<(ng * 1024) / 256, 256, 0, stream>>>(x, xf, K);
    int4mm_kernel<<<N / 64, 256, 0, stream>>>(xf, wp, sc, bias, out, K, N);
}